// Round 1
// 192.981 us; speedup vs baseline: 1.0103x; 1.0103x over previous
//
#include <hip/hip_runtime.h>

#define ROWS_PER_BLOCK 32
#define THREADS 64
#define ROW_F 85        // floats per row
#define NCLS 80         // classes
#define HALF_CLS 40     // classes per lane of a pair
#define CONF_THRESH 0.25f

#define TILE_F (ROWS_PER_BLOCK * ROW_F)   // 2720 floats = 10,880 B
#define TILE_V (TILE_F / 4)               // 680 float4
#define PER_THREAD 10                     // 64*10 = 640; 40 tail vec4
#define TAIL_V (TILE_V - PER_THREAD * THREADS)  // 40

// 32 rows / 10,880 B LDS per single-wave block -> 15 blocks/CU resident
// (vs 7 before): 2.1x waves/SIMD for latency hiding, still no cross-wave
// barrier coupling (__syncthreads in a 1-wave block is just a waitcnt).
// Compute: 2 lanes per row. Each lane scans 40 classes (serial argmax
// phase halved vs 80), pair combined with one __shfl_xor. First-match
// argmax semantics: strict > inside each half keeps the lowest index;
// the high half wins only if strictly greater, so ties resolve to the
// low half = first occurrence, matching jnp.argmax.
// LDS banks: class word idx = 85p + 5 + 40j + k -> bank (21p + 8j + 5+k)%32;
// 21 odd => per fixed k each bank gets exactly one even and one odd lane
// (2-way, free per m136). Box reads are pair-broadcasts (same address).
__global__ __launch_bounds__(THREADS) void yolo_post_kernel(
    const float* __restrict__ in, float* __restrict__ out, int nrows) {
  __shared__ float tile[TILE_F];

  const long long row0 = (long long)blockIdx.x * ROWS_PER_BLOCK;
  const long long base_f = row0 * ROW_F;
  const long long total_f = (long long)nrows * ROW_F;

  const float4* __restrict__ src = (const float4*)(in + base_f);
  float4* dstv = (float4*)tile;
  const int t = threadIdx.x;

  if (base_f + TILE_F <= total_f) {
    // Fast path (always taken when nrows % 32 == 0): issue ALL loads,
    // drain once, then all LDS writes.
    float4 v[PER_THREAD];
#pragma unroll
    for (int k = 0; k < PER_THREAD; ++k) {
      v[k] = src[t + k * THREADS];
    }
    float4 extra;
    if (t < TAIL_V) {
      extra = src[PER_THREAD * THREADS + t];
    }
#pragma unroll
    for (int k = 0; k < PER_THREAD; ++k) {
      dstv[t + k * THREADS] = v[k];
    }
    if (t < TAIL_V) {
      dstv[PER_THREAD * THREADS + t] = extra;
    }
  } else {
    // Guarded tail path (general nrows)
    for (int i = t; i < TILE_V; i += THREADS) {
      if (base_f + (long long)i * 4 + 3 < total_f) dstv[i] = src[i];
    }
  }
  __syncthreads();   // single-wave block: compiles to a waitcnt

  // ---- Compute: one lane PAIR per row ----
  const int p = t >> 1;          // local row
  const int j = t & 1;           // 0 = classes 0..39, 1 = classes 40..79
  const long long r = row0 + p;
  if (r >= nrows) return;        // pair exits together (same r)

  const float* row = tile + p * ROW_F;

  float cx = row[0];
  float cy = row[1];
  float hw = row[2] * 0.5f;
  float hh = row[3] * 0.5f;
  float conf = row[4];

  const float* cls = row + 5 + j * HALF_CLS;
  float best = cls[0];
  int bidx = 0;
#pragma unroll
  for (int c = 1; c < HALF_CLS; ++c) {
    float v = cls[c];
    bool gt = v > best;            // strict > keeps FIRST max in half
    best = gt ? v : best;
    bidx = gt ? c : bidx;
  }

  // Pair combine: both lanes end with identical (bestAll, idxAll).
  float obest = __shfl_xor(best, 1);
  int oidx = __shfl_xor(bidx, 1);

  float bl = j ? obest : best;   // low-half (classes 0..39) result
  int   il = j ? oidx  : bidx;
  float bh = j ? best  : obest;  // high-half (classes 40..79) result
  int   ih = j ? bidx  : oidx;

  bool hi = bh > bl;             // strict >: tie -> low half = first max
  float bestAll = hi ? bh : bl;
  int idxAll = hi ? ih + HALF_CLS : il;

  float score = conf * bestAll;
  bool keep = score > CONF_THRESH;

  float o0 = keep ? cx - hw : 0.0f;
  float o1 = keep ? cy - hh : 0.0f;
  float o2 = keep ? cx + hw : 0.0f;
  float o3 = keep ? cy + hh : 0.0f;
  float o4 = keep ? score : 0.0f;
  float o5 = keep ? (float)idxAll : 0.0f;

  // Split store: even lane writes floats 0..2, odd lane 3..5 ->
  // all 64 lanes store 3 dwords, contiguous 768 B per wave.
  float* op = out + r * 6 + j * 3;
  op[0] = j ? o3 : o0;
  op[1] = j ? o4 : o1;
  op[2] = j ? o5 : o2;
}

extern "C" void kernel_launch(void* const* d_in, const int* in_sizes, int n_in,
                              void* d_out, int out_size, void* d_ws, size_t ws_size,
                              hipStream_t stream) {
  const float* in = (const float*)d_in[0];
  float* out = (float*)d_out;
  const int nrows = in_sizes[0] / ROW_F;                 // 403200
  const int grid = (nrows + ROWS_PER_BLOCK - 1) / ROWS_PER_BLOCK;  // 12600
  yolo_post_kernel<<<grid, THREADS, 0, stream>>>(in, out, nrows);
}